// Round 1
// baseline (23.268 us; speedup 1.0000x reference)
//
#include <hip/hip_runtime.h>

#define TOKEN_DIM 32
#define NQ 16
#define LQ 128
#define ND 128
#define LD 128

__global__ __launch_bounds__(128) void coil_maxsim_kernel(
    const float* __restrict__ doc_reps,   // [ND][LD][TOKEN_DIM]
    const float* __restrict__ qry_reps,   // [NQ][LQ][TOKEN_DIM]
    const float* __restrict__ qry_mask,   // [NQ][LQ]
    const int*   __restrict__ doc_ids,    // [ND][LD]
    const int*   __restrict__ qry_ids,    // [NQ][LQ]
    float*       __restrict__ out)        // [NQ][ND]
{
    __shared__ float s_doc[LD * TOKEN_DIM];   // 16 KB: doc_reps for this doc
    __shared__ int   s_ids[LD];
    __shared__ float s_red[2];

    const int bid = blockIdx.x;
    const int q   = bid / ND;
    const int n   = bid % ND;
    const int tid = threadIdx.x;

    // Stage doc_reps[n] into LDS: 4096 floats = 1024 float4, 128 threads -> 8 each.
    const float4* dsrc = (const float4*)(doc_reps + (size_t)n * LD * TOKEN_DIM);
    float4* ddst = (float4*)s_doc;
    #pragma unroll
    for (int k = 0; k < (LD * TOKEN_DIM / 4) / 128; ++k)
        ddst[tid + k * 128] = dsrc[tid + k * 128];
    s_ids[tid] = doc_ids[n * LD + tid];
    __syncthreads();

    // One query token per thread.
    const int i = tid;
    const float* qv = qry_reps + ((size_t)q * LQ + i) * TOKEN_DIM;
    float4 qr[8];
    #pragma unroll
    for (int k = 0; k < 8; ++k) qr[k] = ((const float4*)qv)[k];
    const int qid = qry_ids[q * LQ + i];

    // MaxSim over doc tokens with exact-match gating.
    float m = -INFINITY;
    int nmatch = 0;
    for (int j = 0; j < LD; ++j) {
        if (s_ids[j] == qid) {
            const float4* dv = (const float4*)(s_doc + j * TOKEN_DIM);
            float acc = 0.f;
            #pragma unroll
            for (int k = 0; k < 8; ++k) {
                float4 d = dv[k];
                acc += qr[k].x * d.x + qr[k].y * d.y + qr[k].z * d.z + qr[k].w * d.w;
            }
            m = fmaxf(m, acc);
            ++nmatch;
        }
    }
    // Non-matching doc tokens contribute 0.0 to the max (jnp.where semantics).
    if (nmatch < LD) m = fmaxf(m, 0.0f);

    float partial = (i >= 1) ? m * qry_mask[q * LQ + i] : 0.0f;

    // Reduce 128 values: butterfly within each 64-lane wave, then combine 2 waves.
    #pragma unroll
    for (int off = 32; off > 0; off >>= 1)
        partial += __shfl_down(partial, off);
    if ((tid & 63) == 0) s_red[tid >> 6] = partial;
    __syncthreads();
    if (tid == 0) out[q * ND + n] = s_red[0] + s_red[1];
}

extern "C" void kernel_launch(void* const* d_in, const int* in_sizes, int n_in,
                              void* d_out, int out_size, void* d_ws, size_t ws_size,
                              hipStream_t stream) {
    const float* doc_reps = (const float*)d_in[0];
    const float* qry_reps = (const float*)d_in[1];
    const float* qry_mask = (const float*)d_in[2];
    const int*   doc_ids  = (const int*)d_in[3];
    const int*   qry_ids  = (const int*)d_in[4];
    float* out = (float*)d_out;

    dim3 grid(NQ * ND);
    dim3 block(128);
    coil_maxsim_kernel<<<grid, block, 0, stream>>>(doc_reps, qry_reps, qry_mask,
                                                   doc_ids, qry_ids, out);
}

// Round 2
// 13.055 us; speedup vs baseline: 1.7823x; 1.7823x over previous
//
#include <hip/hip_runtime.h>

#define TOKEN_DIM 32
#define NQ 16
#define LQ 128
#define ND 128
#define LD 128

__global__ __launch_bounds__(128) void coil_maxsim_kernel(
    const float* __restrict__ doc_reps,   // [ND][LD][TOKEN_DIM]
    const float* __restrict__ qry_reps,   // [NQ][LQ][TOKEN_DIM]
    const float* __restrict__ qry_mask,   // [NQ][LQ]
    const int*   __restrict__ doc_ids,    // [ND][LD]
    const int*   __restrict__ qry_ids,    // [NQ][LQ]
    float*       __restrict__ out)        // [NQ][ND]
{
    __shared__ int   s_ids[LD];
    __shared__ float s_red[2];

    const int bid = blockIdx.x;
    const int q   = bid >> 7;      // bid / ND
    const int n   = bid & 127;     // bid % ND
    const int tid = threadIdx.x;   // one query token i per thread

    s_ids[tid] = doc_ids[n * LD + tid];
    const int qid = qry_ids[q * LQ + tid];
    __syncthreads();

    // ---- Phase 1: build per-lane 128-bit match mask from broadcast LDS reads.
    // 32 x ds_read_b128 (same address across lanes -> broadcast, conflict-free),
    // 128 independent compares -> fully pipelined, no serial dependency.
    unsigned m[4];
    const int4* ids4 = (const int4*)s_ids;
    #pragma unroll
    for (int w = 0; w < 4; ++w) {
        unsigned mm = 0;
        #pragma unroll
        for (int p = 0; p < 8; ++p) {
            int4 a = ids4[w * 8 + p];
            mm |= (unsigned)(a.x == qid) << (4 * p + 0);
            mm |= (unsigned)(a.y == qid) << (4 * p + 1);
            mm |= (unsigned)(a.z == qid) << (4 * p + 2);
            mm |= (unsigned)(a.w == qid) << (4 * p + 3);
        }
        m[w] = mm;
    }
    const int nmatch = __popc(m[0]) + __popc(m[1]) + __popc(m[2]) + __popc(m[3]);

    // ---- Phase 2: lazily load q-vector only on lanes that have a match (~12%).
    float4 qr[8];
    if (nmatch != 0) {
        const float4* qv = (const float4*)(qry_reps + (size_t)(q * LQ + tid) * TOKEN_DIM);
        #pragma unroll
        for (int k = 0; k < 8; ++k) qr[k] = qv[k];
    }

    // ---- Phase 3: walk set bits; doc vectors straight from global (L2-resident).
    // Trip count per wave = max popcount over lanes (~1-2 typical).
    const float4* dbase = (const float4*)(doc_reps + (size_t)n * LD * TOKEN_DIM);
    float best = -INFINITY;
    #pragma unroll
    for (int w = 0; w < 4; ++w) {
        unsigned mm = m[w];
        while (__any(mm != 0)) {
            if (mm) {
                const int j = (w << 5) + __ffs(mm) - 1;
                mm &= mm - 1;
                const float4* dv = dbase + j * (TOKEN_DIM / 4);
                float acc = 0.f;
                #pragma unroll
                for (int k = 0; k < 8; ++k) {
                    float4 d = dv[k];
                    acc += qr[k].x * d.x + qr[k].y * d.y + qr[k].z * d.z + qr[k].w * d.w;
                }
                best = fmaxf(best, acc);
            }
        }
    }
    // jnp.where semantics: non-matching doc tokens contribute 0.0 to the max.
    if (nmatch < LD) best = fmaxf(best, 0.0f);

    // ---- Phase 4: mask, skip [CLS] (i==0), reduce 128 -> 1, store.
    float partial = (tid >= 1) ? best * qry_mask[q * LQ + tid] : 0.0f;
    #pragma unroll
    for (int off = 32; off > 0; off >>= 1)
        partial += __shfl_down(partial, off);
    if ((tid & 63) == 0) s_red[tid >> 6] = partial;
    __syncthreads();
    if (tid == 0) out[q * ND + n] = s_red[0] + s_red[1];
}

extern "C" void kernel_launch(void* const* d_in, const int* in_sizes, int n_in,
                              void* d_out, int out_size, void* d_ws, size_t ws_size,
                              hipStream_t stream) {
    const float* doc_reps = (const float*)d_in[0];
    const float* qry_reps = (const float*)d_in[1];
    const float* qry_mask = (const float*)d_in[2];
    const int*   doc_ids  = (const int*)d_in[3];
    const int*   qry_ids  = (const int*)d_in[4];
    float* out = (float*)d_out;

    coil_maxsim_kernel<<<dim3(NQ * ND), dim3(128), 0, stream>>>(
        doc_reps, qry_reps, qry_mask, doc_ids, qry_ids, out);
}